// Round 6
// baseline (247.642 us; speedup 1.0000x reference)
//
#include <hip/hip_runtime.h>
#include <cstddef>

// Critic_43104291783486 — round 6:
//  (a) amdgpu_waves_per_eu(2,2): force 256-VGPR budget so both depth-2 load
//      batches stay in flight (r5's VGPR=124 proved the compiler serialized:
//      acc(64)+W batches(64)+X(16) > 124).
//  (b) grid 512, each block loops b0 ∈ {ph*128, ph*128+64}; same-node pair =
//      bids (i, i+256) -> same XCD -> weight tiles fetched from HBM once per
//      node, deduped in XCD L2 (concurrent tile set ~1MB << 4MB).
// Structure else = r5: W direct global->reg B-frags (depth-2 even/odd), X
// LDS-staged fp16, v_mfma_f32_16x16x32_f16, f32 accumulate.

#define BN 256   // nodes
#define HD 256   // hidden
#define FD 64    // feature out

#define XS 40    // X lds row stride (fp16): 32 k + 8 pad (80B rows, 16B aligned)
#define HS 264   // h lds row stride (fp16): 256 + 8 pad (528B rows)

typedef _Float16 f16x8 __attribute__((ext_vector_type(8)));
typedef float f32x4 __attribute__((ext_vector_type(4)));

__device__ __forceinline__ f16x8 pack8(const float v[8]) {
  f16x8 r;
#pragma unroll
  for (int i = 0; i < 8; ++i) r[i] = (_Float16)v[i];
  return r;
}

// ---------- X staging: 64 rows x 32 k, fp32 global -> fp16 LDS ----------
__device__ __forceinline__ void x_load(const float* __restrict__ src, int b0, int n,
                                       int kOff, int tid, float4 xr[2]) {
  int row = tid >> 2, ko = (tid & 3) * 8;
  const float* p = src + (size_t)(b0 + row) * (BN * HD) + n * HD + kOff + ko;
  xr[0] = *(const float4*)p;
  xr[1] = *(const float4*)(p + 4);
}
__device__ __forceinline__ void x_loadk(const float* xs0, const float* xs1, int b0,
                                        int n, int kt, int tid, float4 xr[2]) {
  int kOff = kt * 32;
  const float* xs = (kOff < 256) ? xs0 : xs1;   // A-branch switches obs->act at k=256
  x_load(xs, b0, n, kOff & 255, tid, xr);
}
__device__ __forceinline__ void x_write(_Float16* Xl, int tid, const float4 xr[2]) {
  int row = tid >> 2, ko = (tid & 3) * 8;
  const float* f = (const float*)xr;
  f16x8 v;
#pragma unroll
  for (int i = 0; i < 8; ++i) v[i] = (_Float16)f[i];
  *(f16x8*)(Xl + row * XS + ko) = v;   // 16B-aligned (XS*2 = 80)
}

// ---------- W1 B-fragment batch: 4 frags x 8 dwords, stride HD ----------
__device__ __forceinline__ void w1_load(const float* __restrict__ wb, float wf[4][8]) {
#pragma unroll
  for (int nf = 0; nf < 4; ++nf)
#pragma unroll
    for (int j = 0; j < 8; ++j) wf[nf][j] = wb[(size_t)j * HD + nf * 16];
}

// ---------- GEMM1: C(64x256) = X(64xK) @ W(Kx256), K = NK*32, NK even ----------
// wave w owns cols w*64..+63. B-frag elem j (lane l): W[kt*32+(l>>4)*8+j][Nbase+nf*16+(l&15)].
// A-frag (LDS): row = m*16 + (l&15), k contiguous. Layouts verified r3-r5.
#define G1_STEP(KT, WFC, XRC, XRN, XLC, XLN)                                       \
  {                                                                                \
    __syncthreads();                      /* XLC fully written by all waves */     \
    const int kt_ = (KT);                                                          \
    f16x8 bfr[4];                         /* cvt waits batch issued at kt-2 */     \
    _Pragma("unroll") for (int nf = 0; nf < 4; ++nf) bfr[nf] = pack8(WFC[nf]);     \
    if (kt_ + 2 < NK) {                   /* reload freed batches with kt+2 */     \
      w1_load(wb + (size_t)(kt_ + 2) * 32 * HD, WFC);                              \
      x_loadk(xs0, xs1, b0, n, kt_ + 2, tid, XRC);                                 \
    }                                                                              \
    _Pragma("unroll") for (int m = 0; m < 4; ++m) {                                \
      f16x8 a = *(const f16x8*)(XLC + (m * 16 + lrow) * XS + lk * 8);              \
      _Pragma("unroll") for (int nf = 0; nf < 4; ++nf)                             \
        acc[m][nf] =                                                               \
            __builtin_amdgcn_mfma_f32_16x16x32_f16(a, bfr[nf], acc[m][nf], 0, 0, 0); \
    }                                                                              \
    if (kt_ + 1 < NK) x_write(XLN, tid, XRN);  /* XRN issued at kt-1 */            \
  }

template <int NK>
__device__ __forceinline__ void run_gemm1(const float* xs0, const float* xs1,
                                          const float* __restrict__ Wg,
                                          int b0, int n, int tid, int lrow, int lk,
                                          int Nbase, _Float16* Xl0, _Float16* Xl1,
                                          f32x4 acc[4][4]) {
  const float* wb = Wg + (size_t)(lk * 8) * HD + Nbase + lrow;
  float wfA[4][8], wfB[4][8];
  float4 xrA[2], xrB[2];
  x_loadk(xs0, xs1, b0, n, 0, tid, xrA);
  w1_load(wb, wfA);
  x_loadk(xs0, xs1, b0, n, 1, tid, xrB);
  w1_load(wb + (size_t)32 * HD, wfB);
  x_write(Xl0, tid, xrA);                 // waits only oldest (xrA) batch
#pragma unroll 1
  for (int kt = 0; kt < NK; kt += 2) {
    G1_STEP(kt,     wfA, xrA, xrB, Xl0, Xl1)
    G1_STEP(kt + 1, wfB, xrB, xrA, Xl1, Xl0)
  }
  __syncthreads();                        // all X reads done before next use
}

// ---------- h epilogue: relu(C1 + b1) -> fp16 LDS [row][col] ----------
__device__ __forceinline__ void h_write(_Float16* hl, const float* __restrict__ b1g,
                                        int w, int lrow, int lk, const f32x4 acc[4][4]) {
#pragma unroll
  for (int nf = 0; nf < 4; ++nf) {
    int col = w * 64 + nf * 16 + lrow;
    float bv = b1g[col];
#pragma unroll
    for (int m = 0; m < 4; ++m)
#pragma unroll
      for (int r = 0; r < 4; ++r) {
        int row = m * 16 + lk * 4 + r;    // C/D: row=(l>>4)*4+reg, col=l&15
        hl[row * HS + col] = (_Float16)fmaxf(acc[m][nf][r] + bv, 0.f);
      }
  }
}

// ---------- GEMM2: C2(64x64) += h(64x256) @ W2(256x64), depth-2 ----------
__device__ __forceinline__ void w2_load(const float* __restrict__ W2g, int wn, int lrow,
                                        int lk, int s, float wf[2][8]) {
  const float* wb = W2g + (size_t)(s * 32 + lk * 8) * FD + wn * 32 + lrow;
#pragma unroll
  for (int nf = 0; nf < 2; ++nf)
#pragma unroll
    for (int j = 0; j < 8; ++j) wf[nf][j] = wb[j * FD + nf * 16];
}

#define G2_STEP(S, WFC)                                                            \
  {                                                                                \
    const int s_ = (S);                                                            \
    f16x8 bf0 = pack8(WFC[0]), bf1 = pack8(WFC[1]);                                \
    if (s_ + 2 < 8) w2_load(W2g, wn, lrow, lk, s_ + 2, WFC);                       \
    _Pragma("unroll") for (int mf = 0; mf < 2; ++mf) {                             \
      f16x8 a = *(const f16x8*)(hl + (wm * 32 + mf * 16 + lrow) * HS + s_ * 32 + lk * 8); \
      acc2[mf][0] = __builtin_amdgcn_mfma_f32_16x16x32_f16(a, bf0, acc2[mf][0], 0, 0, 0); \
      acc2[mf][1] = __builtin_amdgcn_mfma_f32_16x16x32_f16(a, bf1, acc2[mf][1], 0, 0, 0); \
    }                                                                              \
  }

__global__ __launch_bounds__(256)
__attribute__((amdgpu_waves_per_eu(2, 2)))      // exactly 2 waves/EU -> 256-VGPR budget
void phase1_kernel(
    const float* __restrict__ obs, const float* __restrict__ act,
    const float* __restrict__ V_W1, const float* __restrict__ V_b1,
    const float* __restrict__ V_W2, const float* __restrict__ V_b2,
    const float* __restrict__ A_W1, const float* __restrict__ A_b1,
    const float* __restrict__ A_W2, const float* __restrict__ A_b2,
    float* __restrict__ Q) {
  __shared__ __align__(16) _Float16 Xl[2][64 * XS];   // 10.0 KB
  __shared__ __align__(16) _Float16 hl[64 * HS];      // 33.0 KB => 44 KB total

  int tid = threadIdx.x;
  int l = tid & 63, w = tid >> 6;
  int lrow = l & 15, lk = l >> 4;
  int Nbase = w * 64;
  int wm = w >> 1, wn = w & 1;

  // grid 512: bid & 255 = node, bid >> 8 = pair half. Same-node pair =
  // (i, i+256): same XCD residue (256%8==0) -> concurrent L2 dedupe of weights.
  int bid = blockIdx.x;
  int n  = bid & 255;
  int ph = bid >> 8;

  const float* vW1 = V_W1 + (size_t)n * HD * HD;
  const float* aW1 = A_W1 + (size_t)n * 2 * HD * HD;
  const float* vW2 = V_W2 + (size_t)n * HD * FD;
  const float* aW2 = A_W2 + (size_t)n * HD * FD;

  f32x4 acc[4][4];
  float wfA2[2][8], wfB2[2][8];

#pragma unroll 1
  for (int it = 0; it < 2; ++it) {
    int b0 = ph * 128 + it * 64;

    f32x4 acc2[2][2];
#pragma unroll
    for (int i = 0; i < 2; ++i)
#pragma unroll
      for (int j = 0; j < 2; ++j) acc2[i][j] = (f32x4){0.f, 0.f, 0.f, 0.f};

    // ---------------- V branch ----------------
#pragma unroll
    for (int m = 0; m < 4; ++m)
#pragma unroll
      for (int nf = 0; nf < 4; ++nf) acc[m][nf] = (f32x4){0.f, 0.f, 0.f, 0.f};
    run_gemm1<8>(obs, obs, vW1, b0, n, tid, lrow, lk, Nbase, Xl[0], Xl[1], acc);
    {
      const float* W2g = vW2;
      w2_load(W2g, wn, lrow, lk, 0, wfA2);  // prologue batches fly under
      w2_load(W2g, wn, lrow, lk, 1, wfB2);  // h_write + the publish barrier
      h_write(hl, V_b1 + n * HD, w, lrow, lk, acc);
      __syncthreads();                      // hl published
#pragma unroll 1
      for (int s2 = 0; s2 < 8; s2 += 2) {
        G2_STEP(s2,     wfA2)
        G2_STEP(s2 + 1, wfB2)
      }
      __syncthreads();                      // hl reads done before A overwrites
    }

    // ---------------- A branch ----------------
#pragma unroll
    for (int m = 0; m < 4; ++m)
#pragma unroll
      for (int nf = 0; nf < 4; ++nf) acc[m][nf] = (f32x4){0.f, 0.f, 0.f, 0.f};
    run_gemm1<16>(obs, act, aW1, b0, n, tid, lrow, lk, Nbase, Xl[0], Xl[1], acc);
    {
      const float* W2g = aW2;
      w2_load(W2g, wn, lrow, lk, 0, wfA2);
      w2_load(W2g, wn, lrow, lk, 1, wfB2);
      h_write(hl, A_b1 + n * HD, w, lrow, lk, acc);
      __syncthreads();
#pragma unroll 1
      for (int s2 = 0; s2 < 8; s2 += 2) {
        G2_STEP(s2,     wfA2)
        G2_STEP(s2 + 1, wfB2)
      }
    }

    // ---------------- Q = acc2 + V_b2 + A_b2 ----------------
    const float* vb2 = V_b2 + n * FD;
    const float* ab2 = A_b2 + n * FD;
#pragma unroll
    for (int mf = 0; mf < 2; ++mf)
#pragma unroll
      for (int nf = 0; nf < 2; ++nf) {
        int f = wn * 32 + nf * 16 + lrow;
        float bias = vb2[f] + ab2[f];
#pragma unroll
        for (int rr = 0; rr < 4; ++rr) {
          int row = b0 + wm * 32 + mf * 16 + lk * 4 + rr;
          Q[(size_t)row * (BN * FD) + n * FD + f] = acc2[mf][nf][rr] + bias;
        }
      }
    // next iteration's LDS writes are ordered behind run_gemm1's internal
    // barriers; no extra barrier needed here.
  }
}

// ---------------- phase 2: gather + subset-min + chi + mean ----------------
__global__ __launch_bounds__(256) void phase2_kernel(const float* __restrict__ Q,
                                                     const float* __restrict__ chi_m,
                                                     const int* __restrict__ le,
                                                     float* __restrict__ out) {
  int b = blockIdx.x;
  int n = threadIdx.x;
  // int64-vs-int32 layout hedge: centers = arange(N) => int32 layout has le[5]==1.
  int step = (le[5] == 1) ? 1 : 2;
  const int* e = le + n * 5 * step;
  int c  = e[0 * step] & (BN - 1);
  int n0 = e[1 * step] & (BN - 1);
  int n1 = e[2 * step] & (BN - 1);
  int n2 = e[3 * step] & (BN - 1);
  int n3 = e[4 * step] & (BN - 1);
  const float* ch = chi_m + n * 45;     // (HEADS=3, S=15)
  float cm[15];
#pragma unroll
  for (int s = 0; s < 15; ++s) cm[s] = (ch[s] + ch[15 + s] + ch[30 + s]) * (1.f / 3.f);
  const float* qb = Q + (size_t)b * (BN * FD);
  const float* q0 = qb + n0 * FD;
  const float* q1 = qb + n1 * FD;
  const float* q2 = qb + n2 * FD;
  const float* q3 = qb + n3 * FD;
  const float* qc = qb + c * FD;
  float acc = 0.f;
#pragma unroll
  for (int f = 0; f < FD; f += 4) {
    float4 v0 = *(const float4*)(q0 + f);
    float4 v1 = *(const float4*)(q1 + f);
    float4 v2 = *(const float4*)(q2 + f);
    float4 v3 = *(const float4*)(q3 + f);
    float4 vc = *(const float4*)(qc + f);
    const float* p0 = (const float*)&v0;
    const float* p1 = (const float*)&v1;
    const float* p2 = (const float*)&v2;
    const float* p3 = (const float*)&v3;
    const float* pc = (const float*)&vc;
#pragma unroll
    for (int u = 0; u < 4; ++u) {
      float a = p0[u], bq = p1[u], cq = p2[u], d = p3[u];
      float m01 = fminf(a, bq), m02 = fminf(a, cq), m03 = fminf(a, d);
      float m12 = fminf(bq, cq), m13 = fminf(bq, d), m23 = fminf(cq, d);
      float m012 = fminf(m01, cq), m013 = fminf(m01, d);
      float m023 = fminf(m02, d),  m123 = fminf(m12, d);
      float m0123 = fminf(m01, m23);
      float chi = cm[0] * a   + cm[1] * bq   + cm[2] * m01  + cm[3] * cq
                + cm[4] * m02 + cm[5] * m12  + cm[6] * m012 + cm[7] * d
                + cm[8] * m03 + cm[9] * m13  + cm[10] * m013 + cm[11] * m23
                + cm[12] * m023 + cm[13] * m123 + cm[14] * m0123;
      acc += chi + pc[u];
    }
  }
  out[b * BN + n] = acc * (1.f / 64.f);
}

extern "C" void kernel_launch(void* const* d_in, const int* in_sizes, int n_in,
                              void* d_out, int out_size, void* d_ws, size_t ws_size,
                              hipStream_t stream) {
  (void)in_sizes; (void)n_in; (void)out_size; (void)ws_size;
  const float* obs  = (const float*)d_in[0];
  const float* act  = (const float*)d_in[1];
  const float* V_W1 = (const float*)d_in[2];
  const float* V_b1 = (const float*)d_in[3];
  const float* V_W2 = (const float*)d_in[4];
  const float* V_b2 = (const float*)d_in[5];
  const float* A_W1 = (const float*)d_in[6];
  const float* A_b1 = (const float*)d_in[7];
  const float* A_W2 = (const float*)d_in[8];
  const float* A_b2 = (const float*)d_in[9];
  const float* chim = (const float*)d_in[10];
  const int*   le   = (const int*)d_in[11];
  float* Q   = (float*)d_ws;            // 16 MB scratch: Q[B][N][F]
  float* out = (float*)d_out;

  phase1_kernel<<<dim3(512), dim3(256), 0, stream>>>(obs, act, V_W1, V_b1, V_W2, V_b2,
                                                     A_W1, A_b1, A_W2, A_b2, Q);
  phase2_kernel<<<dim3(256), dim3(256), 0, stream>>>(Q, chim, le, out);
}

// Round 7
// 151.989 us; speedup vs baseline: 1.6293x; 1.6293x over previous
//
#include <hip/hip_runtime.h>
#include <cstddef>

// Critic_43104291783486 — round 7: HBM-pump redesign.
// grid=256 (1 node per block per CU), BM=256 (all batch rows) -> every weight
// byte fetched from HBM exactly once. W staged fp32 via global_load_lds (zero
// VGPR cost -> allocator can't serialize it). X reg-staged fp16, depth-2.
// GEMM2 via register-h -> transposed LDS slab bounce. Manual counted vmcnt +
// raw s_barrier in the hot loop keeps prefetch in flight across barriers.

#define BN 256
#define HD 256
#define FD 64
#define XS 40    // X lds row stride fp16 (80B, 16B-aligned, 2-way-free reads)
#define SLS 266  // slab row stride fp16 (532B -> conflict-free frag reads)

typedef _Float16 f16x8 __attribute__((ext_vector_type(8)));
typedef _Float16 f16x4 __attribute__((ext_vector_type(4)));
typedef float f32x4 __attribute__((ext_vector_type(4)));

#define GLOAD16(g, l)                                              \
  __builtin_amdgcn_global_load_lds(                                \
      (__attribute__((address_space(1))) void*)(g),                \
      (__attribute__((address_space(3))) void*)(l), 16, 0, 0)

// ---------- X staging: 256 rows x 32 k, fp32 global -> regs -> fp16 LDS ----------
__device__ __forceinline__ void x_load(const float* xs0, const float* xs1, int n,
                                       int kt, int tid, float4 xr[8]) {
  int kOff = kt * 32;
  const float* xs = (kOff < 256) ? xs0 : xs1;   // A-branch: obs then act
  const float* p = xs + (size_t)tid * (BN * HD) + (size_t)n * HD + (kOff & 255);
#pragma unroll
  for (int i = 0; i < 8; ++i) xr[i] = *(const float4*)(p + i * 4);
}
__device__ __forceinline__ void x_write(_Float16* Xl, int tid, const float4 xr[8]) {
  const float* f = (const float*)xr;
  _Float16* d = Xl + tid * XS;
#pragma unroll
  for (int i = 0; i < 4; ++i) {
    f16x8 v;
#pragma unroll
    for (int j = 0; j < 8; ++j) v[j] = (_Float16)f[i * 8 + j];
    *(f16x8*)(d + i * 8) = v;
  }
}

// ---------- W1 tile gload: 32 k-rows x 256 cols fp32 -> LDS [32][256] ----------
__device__ __forceinline__ void w_gload(const float* Wg, float* Wn, int ktile,
                                        int w, int lane) {
#pragma unroll
  for (int s = 0; s < 8; ++s) {
    const float* src = Wg + (size_t)(ktile * 32 + w * 8 + s) * HD + lane * 4;
    float* dst = Wn + (w * 8 + s) * 256;   // wave-uniform base; HW adds lane*16B
    GLOAD16(src, dst);
  }
}

// ---------- GEMM1 compute: one 32-k step, 64 MFMA/wave ----------
// A-frag: row = m*16+(l&15), k contiguous (verified r3-r6).
// B-frag: col = Nbase+nf*16+(l&15), k = (l>>4)*8+j (fp32 LDS scalar reads + cvt).
__device__ __forceinline__ void g1_compute(const float* Wc, const _Float16* Xc,
                                           int lrow, int lk8, int Nbase,
                                           f32x4 acc[16][4]) {
  f16x8 b[4];
#pragma unroll
  for (int nf = 0; nf < 4; ++nf) {
    const float* p = Wc + lk8 * 256 + Nbase + nf * 16 + lrow;
    f16x8 t;
#pragma unroll
    for (int j = 0; j < 8; ++j) t[j] = (_Float16)p[j * 256];
    b[nf] = t;
  }
#pragma unroll
  for (int m = 0; m < 16; ++m) {
    f16x8 a = *(const f16x8*)(Xc + (m * 16 + lrow) * XS + lk8);
#pragma unroll
    for (int nf = 0; nf < 4; ++nf)
      acc[m][nf] = __builtin_amdgcn_mfma_f32_16x16x32_f16(a, b[nf], acc[m][nf], 0, 0, 0);
  }
}

#define WAIT_BAR(VMCNT_STR)                                        \
  asm volatile("s_waitcnt " VMCNT_STR " lgkmcnt(0)" ::: "memory"); \
  __builtin_amdgcn_s_barrier();                                    \
  asm volatile("" ::: "memory");

// C(256x256) = X(256xK) @ W(Kx256), K = NK*32, NK even >= 4.
template <int NK>
__device__ __forceinline__ void run_gemm1(const float* xs0, const float* xs1,
                                          const float* Wg, int n, int tid,
                                          int lrow, int lk8, int Nbase, int w, int lane,
                                          float* Wl0, float* Wl1,
                                          _Float16* Xl0, _Float16* Xl1,
                                          f32x4 acc[16][4]) {
  float4 xrA[8], xrB[8];
  w_gload(Wg, Wl0, 0, w, lane);
  x_load(xs0, xs1, n, 0, tid, xrA);
  x_load(xs0, xs1, n, 1, tid, xrB);
  x_write(Xl0, tid, xrA);        // compiler's wait drains X(0) (and W(0), FIFO)
  __syncthreads();
#pragma unroll 1
  for (int kt = 0; kt < NK - 2; kt += 2) {
    // even step: compute (Wl0, Xl0); prefetch W(kt+1)->Wl1, X(kt+2)->xrA
    w_gload(Wg, Wl1, kt + 1, w, lane);
    x_load(xs0, xs1, n, kt + 2, tid, xrA);
    g1_compute(Wl0, Xl0, lrow, lk8, Nbase, acc);
    x_write(Xl1, tid, xrB);      // X(kt+1) -> Xl1
    WAIT_BAR("vmcnt(8)")         // drain my W(kt+1); X(kt+2) stays in flight
    // odd step: compute (Wl1, Xl1); prefetch W(kt+2)->Wl0, X(kt+3)->xrB
    w_gload(Wg, Wl0, kt + 2, w, lane);
    x_load(xs0, xs1, n, kt + 3, tid, xrB);
    g1_compute(Wl1, Xl1, lrow, lk8, Nbase, acc);
    x_write(Xl0, tid, xrA);      // X(kt+2) -> Xl0
    WAIT_BAR("vmcnt(8)")
  }
  // TAIL1: kt = NK-2 (even)
  w_gload(Wg, Wl1, NK - 1, w, lane);
  g1_compute(Wl0, Xl0, lrow, lk8, Nbase, acc);
  x_write(Xl1, tid, xrB);        // X(NK-1)
  WAIT_BAR("vmcnt(0)")
  // TAIL2: kt = NK-1 (odd)
  g1_compute(Wl1, Xl1, lrow, lk8, Nbase, acc);
  // caller must __syncthreads() before reusing LDS
}

// ---------- branch epilogue: h = relu(C1+b1) -> slabs -> C2 += h @ W2 ----------
__device__ __forceinline__ void gemm2_branch(f32x4 acc[16][4], f32x4 acc2[4][4],
                                             const float* W2g, const float* b1g,
                                             float* W_lds, _Float16* slab,
                                             int tid, int lrow, int lq, int lk8,
                                             int Nbase, int w, int lane) {
  // W2 (256x64 fp32 = 64KB) -> W_lds (reuses both W1 buffers), linear copy
#pragma unroll
  for (int s = 0; s < 16; ++s) {
    const float* src = W2g + (w * 16 + s) * 256 + lane * 4;
    float* dst = W_lds + (w * 16 + s) * 256;
    GLOAD16(src, dst);
  }
  // h in registers (C-layout): row = m*16+lq*4+r, col = Nbase+nf*16+lrow
  float bv[4];
#pragma unroll
  for (int nf = 0; nf < 4; ++nf) bv[nf] = b1g[Nbase + nf * 16 + lrow];
  f16x4 h_reg[16][4];
#pragma unroll
  for (int m = 0; m < 16; ++m)
#pragma unroll
    for (int nf = 0; nf < 4; ++nf) {
      f16x4 hv;
#pragma unroll
      for (int r = 0; r < 4; ++r)
        hv[r] = (_Float16)fmaxf(acc[m][nf][r] + bv[nf], 0.f);
      h_reg[m][nf] = hv;
    }
  __syncthreads();   // W2 arrived (vmcnt(0) drain) + all waves ready
  // 4 k-slabs: slab s = C1 cols s*64..+63 = wave s's registers.
  // transposed slab [klocal][row]: b64 writes (r contiguous), padded reads.
#pragma unroll 1
  for (int s = 0; s < 4; ++s) {
    if (w == s) {
#pragma unroll
      for (int m = 0; m < 16; ++m)
#pragma unroll
        for (int nf = 0; nf < 4; ++nf)
          *(f16x4*)(slab + (nf * 16 + lrow) * SLS + m * 16 + lq * 4) = h_reg[m][nf];
    }
    __syncthreads();
#pragma unroll
    for (int kf = 0; kf < 2; ++kf) {
      f16x8 a[4], bb[4];
#pragma unroll
      for (int mf = 0; mf < 4; ++mf) {
        f16x8 t;
#pragma unroll
        for (int j = 0; j < 8; ++j)
          t[j] = slab[(kf * 32 + lk8 + j) * SLS + w * 64 + mf * 16 + lrow];
        a[mf] = t;
      }
#pragma unroll
      for (int nf = 0; nf < 4; ++nf) {
        const float* p = W_lds + (s * 64 + kf * 32 + lk8) * 64 + nf * 16 + lrow;
        f16x8 t;
#pragma unroll
        for (int j = 0; j < 8; ++j) t[j] = (_Float16)p[j * 64];
        bb[nf] = t;
      }
#pragma unroll
      for (int mf = 0; mf < 4; ++mf)
#pragma unroll
        for (int nf = 0; nf < 4; ++nf)
          acc2[mf][nf] =
              __builtin_amdgcn_mfma_f32_16x16x32_f16(a[mf], bb[nf], acc2[mf][nf], 0, 0, 0);
    }
    __syncthreads();
  }
}

__global__ __launch_bounds__(256, 1) void phase1_kernel(
    const float* __restrict__ obs, const float* __restrict__ act,
    const float* __restrict__ V_W1, const float* __restrict__ V_b1,
    const float* __restrict__ V_W2, const float* __restrict__ V_b2,
    const float* __restrict__ A_W1, const float* __restrict__ A_b1,
    const float* __restrict__ A_W2, const float* __restrict__ A_b2,
    float* __restrict__ Q) {
  __shared__ float W_lds[16384];                       // 64KB: W1 dbuf / W2 full
  __shared__ __align__(16) _Float16 Xl[2][256 * XS];   // 40KB
  __shared__ __align__(16) _Float16 slab[64 * SLS];    // 34KB   => 138KB total
  float* Wl0 = W_lds;
  float* Wl1 = W_lds + 8192;

  int tid = threadIdx.x;
  int l = tid & 63, w = tid >> 6, lane = l;
  int lrow = l & 15, lq = l >> 4, lk8 = lq * 8;
  int Nbase = w * 64;
  int n = blockIdx.x;                 // 1 node per block per CU

  f32x4 acc[16][4];
  f32x4 acc2[4][4];
#pragma unroll
  for (int i = 0; i < 4; ++i)
#pragma unroll
    for (int j = 0; j < 4; ++j) acc2[i][j] = (f32x4){0.f, 0.f, 0.f, 0.f};

  // ---------------- V branch ----------------
#pragma unroll
  for (int m = 0; m < 16; ++m)
#pragma unroll
    for (int nf = 0; nf < 4; ++nf) acc[m][nf] = (f32x4){0.f, 0.f, 0.f, 0.f};
  run_gemm1<8>(obs, obs, V_W1 + (size_t)n * HD * HD, n, tid, lrow, lk8, Nbase,
               w, lane, Wl0, Wl1, Xl[0], Xl[1], acc);
  __syncthreads();                    // all waves done with W1/X LDS
  gemm2_branch(acc, acc2, V_W2 + (size_t)n * HD * FD, V_b1 + n * HD,
               W_lds, slab, tid, lrow, lq, lk8, Nbase, w, lane);

  // ---------------- A branch ----------------
#pragma unroll
  for (int m = 0; m < 16; ++m)
#pragma unroll
    for (int nf = 0; nf < 4; ++nf) acc[m][nf] = (f32x4){0.f, 0.f, 0.f, 0.f};
  run_gemm1<16>(obs, act, A_W1 + (size_t)n * 2 * HD * HD, n, tid, lrow, lk8, Nbase,
                w, lane, Wl0, Wl1, Xl[0], Xl[1], acc);
  __syncthreads();
  gemm2_branch(acc, acc2, A_W2 + (size_t)n * HD * FD, A_b1 + n * HD,
               W_lds, slab, tid, lrow, lq, lk8, Nbase, w, lane);

  // ---------------- Q = acc2 + V_b2 + A_b2 ----------------
  const float* vb2 = V_b2 + n * FD;
  const float* ab2 = A_b2 + n * FD;
#pragma unroll
  for (int mf = 0; mf < 4; ++mf)
#pragma unroll
    for (int nf = 0; nf < 4; ++nf) {
      int f = nf * 16 + lrow;
      float bias = vb2[f] + ab2[f];
#pragma unroll
      for (int rr = 0; rr < 4; ++rr) {
        int row = w * 64 + mf * 16 + lq * 4 + rr;
        Q[(size_t)row * (BN * FD) + n * FD + f] = acc2[mf][nf][rr] + bias;
      }
    }
}

// ---------------- phase 2: gather + subset-min + chi + mean ----------------
__global__ __launch_bounds__(256) void phase2_kernel(const float* __restrict__ Q,
                                                     const float* __restrict__ chi_m,
                                                     const int* __restrict__ le,
                                                     float* __restrict__ out) {
  int b = blockIdx.x;
  int n = threadIdx.x;
  // int64-vs-int32 layout hedge: centers = arange(N) => int32 layout has le[5]==1.
  int step = (le[5] == 1) ? 1 : 2;
  const int* e = le + n * 5 * step;
  int c  = e[0 * step] & (BN - 1);
  int n0 = e[1 * step] & (BN - 1);
  int n1 = e[2 * step] & (BN - 1);
  int n2 = e[3 * step] & (BN - 1);
  int n3 = e[4 * step] & (BN - 1);
  const float* ch = chi_m + n * 45;   // (HEADS=3, S=15)
  float cm[15];
#pragma unroll
  for (int s = 0; s < 15; ++s) cm[s] = (ch[s] + ch[15 + s] + ch[30 + s]) * (1.f / 3.f);
  const float* qb = Q + (size_t)b * (BN * FD);
  const float* q0 = qb + n0 * FD;
  const float* q1 = qb + n1 * FD;
  const float* q2 = qb + n2 * FD;
  const float* q3 = qb + n3 * FD;
  const float* qc = qb + c * FD;
  float acc = 0.f;
#pragma unroll
  for (int f = 0; f < FD; f += 4) {
    float4 v0 = *(const float4*)(q0 + f);
    float4 v1 = *(const float4*)(q1 + f);
    float4 v2 = *(const float4*)(q2 + f);
    float4 v3 = *(const float4*)(q3 + f);
    float4 vc = *(const float4*)(qc + f);
    const float* p0 = (const float*)&v0;
    const float* p1 = (const float*)&v1;
    const float* p2 = (const float*)&v2;
    const float* p3 = (const float*)&v3;
    const float* pc = (const float*)&vc;
#pragma unroll
    for (int u = 0; u < 4; ++u) {
      float a = p0[u], bq = p1[u], cq = p2[u], d = p3[u];
      float m01 = fminf(a, bq), m02 = fminf(a, cq), m03 = fminf(a, d);
      float m12 = fminf(bq, cq), m13 = fminf(bq, d), m23 = fminf(cq, d);
      float m012 = fminf(m01, cq), m013 = fminf(m01, d);
      float m023 = fminf(m02, d),  m123 = fminf(m12, d);
      float m0123 = fminf(m01, m23);
      float chi = cm[0] * a   + cm[1] * bq   + cm[2] * m01  + cm[3] * cq
                + cm[4] * m02 + cm[5] * m12  + cm[6] * m012 + cm[7] * d
                + cm[8] * m03 + cm[9] * m13  + cm[10] * m013 + cm[11] * m23
                + cm[12] * m023 + cm[13] * m123 + cm[14] * m0123;
      acc += chi + pc[u];
    }
  }
  out[b * BN + n] = acc * (1.f / 64.f);
}

extern "C" void kernel_launch(void* const* d_in, const int* in_sizes, int n_in,
                              void* d_out, int out_size, void* d_ws, size_t ws_size,
                              hipStream_t stream) {
  (void)in_sizes; (void)n_in; (void)out_size; (void)ws_size;
  const float* obs  = (const float*)d_in[0];
  const float* act  = (const float*)d_in[1];
  const float* V_W1 = (const float*)d_in[2];
  const float* V_b1 = (const float*)d_in[3];
  const float* V_W2 = (const float*)d_in[4];
  const float* V_b2 = (const float*)d_in[5];
  const float* A_W1 = (const float*)d_in[6];
  const float* A_b1 = (const float*)d_in[7];
  const float* A_W2 = (const float*)d_in[8];
  const float* A_b2 = (const float*)d_in[9];
  const float* chim = (const float*)d_in[10];
  const int*   le   = (const int*)d_in[11];
  float* Q   = (float*)d_ws;            // 16 MB scratch: Q[B][N][F]
  float* out = (float*)d_out;

  phase1_kernel<<<dim3(256), dim3(256), 0, stream>>>(obs, act, V_W1, V_b1, V_W2, V_b2,
                                                     A_W1, A_b1, A_W2, A_b2, Q);
  phase2_kernel<<<dim3(256), dim3(256), 0, stream>>>(Q, chim, le, out);
}

// Round 8
// 117.539 us; speedup vs baseline: 2.1069x; 1.2931x over previous
//
#include <hip/hip_runtime.h>
#include <cstddef>

// Critic_43104291783486 — round 8: occupancy fix for the weights-once design.
// grid=256 (1 node/block/CU) but 512 threads / 8 waves per block:
// per-wave acc[8][4]=128 regs -> total <=~230 -> 2 waves/SIMD (vs r7's 1).
// X loads page-local (8 rows/instr instead of 32). W via global_load_lds
// (zero VGPR). Counted-vmcnt schedule scaled to 4-wide batches.

#define BN 256
#define HD 256
#define FD 64
#define XS 40    // X lds row stride (halves): 32 k + 8 pad (80B rows)
#define SLS 268  // slab row stride (halves): 256 rows + 12 pad (536B, 8B-mult)

typedef _Float16 f16x8 __attribute__((ext_vector_type(8)));
typedef _Float16 f16x4 __attribute__((ext_vector_type(4)));
typedef float f32x4 __attribute__((ext_vector_type(4)));

#define GLOAD16(g, l)                                              \
  __builtin_amdgcn_global_load_lds(                                \
      (__attribute__((address_space(1))) void*)(g),                \
      (__attribute__((address_space(3))) void*)(l), 16, 0, 0)

#define WAIT_BAR(VMCNT_STR)                                        \
  asm volatile("s_waitcnt " VMCNT_STR " lgkmcnt(0)" ::: "memory"); \
  __builtin_amdgcn_s_barrier();                                    \
  asm volatile("" ::: "memory");

// ---------- X staging: 256 rows x 32 k fp32 -> regs -> fp16 LDS ----------
// Page-local: instr i reads 8 rows x 8 lanes x 16B (one 128B k-slice per row).
__device__ __forceinline__ void x_load(const float* xs0, const float* xs1, int n,
                                       int kt, int tid, float4 xr[4]) {
  int kOff = kt * 32;
  const float* xs = (kOff < 256) ? xs0 : xs1;   // A-branch: obs then act
  int l = tid & 63, w = tid >> 6;
  const float* base = xs + (size_t)n * HD + (kOff & 255) + (l & 7) * 4;
#pragma unroll
  for (int i = 0; i < 4; ++i) {
    int row = w * 32 + i * 8 + (l >> 3);
    xr[i] = *(const float4*)(base + (size_t)row * (BN * HD));
  }
}
__device__ __forceinline__ void x_write(_Float16* Xl, int tid, const float4 xr[4]) {
  int l = tid & 63, w = tid >> 6;
#pragma unroll
  for (int i = 0; i < 4; ++i) {
    int row = w * 32 + i * 8 + (l >> 3);
    f16x4 v;
    v[0] = (_Float16)xr[i].x; v[1] = (_Float16)xr[i].y;
    v[2] = (_Float16)xr[i].z; v[3] = (_Float16)xr[i].w;
    *(f16x4*)(Xl + row * XS + (l & 7) * 4) = v;   // 8B-aligned b64
  }
}

// ---------- W1 tile gload: 32 k-rows x 256 cols fp32 -> LDS [32][256] ----------
__device__ __forceinline__ void w_gload(const float* Wg, float* Wl, int ktile,
                                        int w, int lane) {
#pragma unroll
  for (int s = 0; s < 4; ++s) {
    const float* src = Wg + (size_t)(ktile * 32 + w * 4 + s) * HD + lane * 4;
    float* dst = Wl + (w * 4 + s) * 256;   // wave-uniform base; HW adds lane*16B
    GLOAD16(src, dst);
  }
}

// ---------- GEMM1 compute: one 32-k step, 32 MFMA/wave ----------
// A-frag: row = wm1*128 + m*16 + (l&15), k = lq*8+j (verified r3-r7 layout).
// B-frag: col = wn1*64 + nf*16 + (l&15), k = lq*8+j (fp32 LDS scalar + cvt).
__device__ __forceinline__ void g1_compute(const float* Wc, const _Float16* Xc,
                                           int lrow, int lk8, int Nbase, int wm1,
                                           f32x4 acc[8][4]) {
  f16x8 b[4];
#pragma unroll
  for (int nf = 0; nf < 4; ++nf) {
    const float* p = Wc + lk8 * 256 + Nbase + nf * 16 + lrow;
    f16x8 t;
#pragma unroll
    for (int j = 0; j < 8; ++j) t[j] = (_Float16)p[j * 256];
    b[nf] = t;
  }
#pragma unroll
  for (int m = 0; m < 8; ++m) {
    f16x8 a = *(const f16x8*)(Xc + (wm1 * 128 + m * 16 + lrow) * XS + lk8);
#pragma unroll
    for (int nf = 0; nf < 4; ++nf)
      acc[m][nf] = __builtin_amdgcn_mfma_f32_16x16x32_f16(a, b[nf], acc[m][nf], 0, 0, 0);
  }
}

// C(256x256) = X(256xK) @ W(Kx256), K = NK*32, NK even >= 4.
template <int NK>
__device__ __forceinline__ void run_gemm1(const float* xs0, const float* xs1,
                                          const float* Wg, int n, int tid,
                                          int lrow, int lk8, int Nbase, int wm1,
                                          int w, int lane,
                                          float* Wl0, float* Wl1,
                                          _Float16* Xl0, _Float16* Xl1,
                                          f32x4 acc[8][4]) {
  float4 xrA[4], xrB[4];
  w_gload(Wg, Wl0, 0, w, lane);
  x_load(xs0, xs1, n, 0, tid, xrA);
  x_load(xs0, xs1, n, 1, tid, xrB);
  x_write(Xl0, tid, xrA);        // implicit wait drains W(0)+X(0); X(1) stays
  __syncthreads();
#pragma unroll 1
  for (int kt = 0; kt < NK - 2; kt += 2) {
    // even: compute (Wl0,Xl0); prefetch W(kt+1)->Wl1, X(kt+2)->xrA
    w_gload(Wg, Wl1, kt + 1, w, lane);
    x_load(xs0, xs1, n, kt + 2, tid, xrA);
    g1_compute(Wl0, Xl0, lrow, lk8, Nbase, wm1, acc);
    x_write(Xl1, tid, xrB);      // X(kt+1) -> Xl1 (issued last step: landed)
    WAIT_BAR("vmcnt(4)")         // drain W(kt+1); X(kt+2) stays in flight
    // odd: compute (Wl1,Xl1); prefetch W(kt+2)->Wl0, X(kt+3)->xrB
    w_gload(Wg, Wl0, kt + 2, w, lane);
    x_load(xs0, xs1, n, kt + 3, tid, xrB);
    g1_compute(Wl1, Xl1, lrow, lk8, Nbase, wm1, acc);
    x_write(Xl0, tid, xrA);
    WAIT_BAR("vmcnt(4)")
  }
  // tail: kt = NK-2 (even)
  w_gload(Wg, Wl1, NK - 1, w, lane);
  g1_compute(Wl0, Xl0, lrow, lk8, Nbase, wm1, acc);
  x_write(Xl1, tid, xrB);        // waits X(NK-1) (older than W(NK-1))
  WAIT_BAR("vmcnt(0)")
  // tail: kt = NK-1 (odd)
  g1_compute(Wl1, Xl1, lrow, lk8, Nbase, wm1, acc);
  // caller must __syncthreads() before reusing LDS
}

// ---------- GEMM2: C2(256x64) += relu(C1+b1) @ W2(256x64) via slab bounce ----------
// C2 wave-grid 8M x 1N: wave w owns rows w*32..+31, acc2[2][4].
__device__ __forceinline__ void gemm2_branch(f32x4 acc[8][4], f32x4 acc2[2][4],
                                             const float* W2g, const float* b1g,
                                             float* W_lds, _Float16* slab,
                                             int lrow, int lq, int lk8,
                                             int Nbase, int wm1, int wn1,
                                             int w, int lane) {
  // W2 (256x64 fp32 = 64KB) -> W_lds, linear gload copy (8KB/wave)
#pragma unroll
  for (int s = 0; s < 8; ++s) {
    int off = w * 2048 + s * 256;
    GLOAD16(W2g + off + lane * 4, W_lds + off);
  }
  float bv[4];
#pragma unroll
  for (int nf = 0; nf < 4; ++nf) bv[nf] = b1g[Nbase + nf * 16 + lrow];
  // 4 k-slabs: slab s = C1 cols s*64..+63, held by the 2 waves with wn1==s.
  // slab layout transposed [klocal 0..63][row 0..255(+pad)] fp16.
#pragma unroll 1
  for (int s = 0; s < 4; ++s) {
    if (wn1 == s) {
#pragma unroll
      for (int m = 0; m < 8; ++m)
#pragma unroll
        for (int nf = 0; nf < 4; ++nf) {
          f16x4 hv;
#pragma unroll
          for (int r = 0; r < 4; ++r)
            hv[r] = (_Float16)fmaxf(acc[m][nf][r] + bv[nf], 0.f);
          *(f16x4*)(slab + (nf * 16 + lrow) * SLS + wm1 * 128 + m * 16 + lq * 4) = hv;
        }
    }
    __syncthreads();   // slab visible; at s==0 also drains the W2 gloads
#pragma unroll
    for (int kf = 0; kf < 2; ++kf) {
      f16x8 a[2], bb[4];
#pragma unroll
      for (int mf = 0; mf < 2; ++mf) {
        f16x8 t;
#pragma unroll
        for (int j = 0; j < 8; ++j)
          t[j] = slab[(kf * 32 + lk8 + j) * SLS + w * 32 + mf * 16 + lrow];
        a[mf] = t;
      }
#pragma unroll
      for (int nf = 0; nf < 4; ++nf) {
        const float* p = W_lds + (s * 64 + kf * 32 + lk8) * 64 + nf * 16 + lrow;
        f16x8 t;
#pragma unroll
        for (int j = 0; j < 8; ++j) t[j] = (_Float16)p[j * 64];
        bb[nf] = t;
      }
#pragma unroll
      for (int mf = 0; mf < 2; ++mf)
#pragma unroll
        for (int nf = 0; nf < 4; ++nf)
          acc2[mf][nf] =
              __builtin_amdgcn_mfma_f32_16x16x32_f16(a[mf], bb[nf], acc2[mf][nf], 0, 0, 0);
    }
    __syncthreads();   // slab reads done before next round overwrites
  }
}

__global__ __launch_bounds__(512, 2) void phase1_kernel(
    const float* __restrict__ obs, const float* __restrict__ act,
    const float* __restrict__ V_W1, const float* __restrict__ V_b1,
    const float* __restrict__ V_W2, const float* __restrict__ V_b2,
    const float* __restrict__ A_W1, const float* __restrict__ A_b1,
    const float* __restrict__ A_W2, const float* __restrict__ A_b2,
    float* __restrict__ Q) {
  __shared__ float W_lds[16384];                       // 64KB: W1 dbuf / W2
  __shared__ __align__(16) _Float16 Xl[2][256 * XS];   // 40KB
  __shared__ __align__(16) _Float16 slab[64 * SLS];    // 33.5KB => ~138KB
  float* Wl0 = W_lds;
  float* Wl1 = W_lds + 8192;

  int tid = threadIdx.x;
  int l = tid & 63, w = tid >> 6, lane = l;
  int lrow = l & 15, lq = l >> 4, lk8 = lq * 8;
  int wm1 = w >> 2, wn1 = w & 3;      // GEMM1 wave grid 2M x 4N
  int Nbase = wn1 * 64;
  int n = blockIdx.x;                 // 1 node per block per CU

  f32x4 acc[8][4];
  f32x4 acc2[2][4];
#pragma unroll
  for (int i = 0; i < 2; ++i)
#pragma unroll
    for (int j = 0; j < 4; ++j) acc2[i][j] = (f32x4){0.f, 0.f, 0.f, 0.f};

  // ---------------- V branch ----------------
#pragma unroll
  for (int m = 0; m < 8; ++m)
#pragma unroll
    for (int nf = 0; nf < 4; ++nf) acc[m][nf] = (f32x4){0.f, 0.f, 0.f, 0.f};
  run_gemm1<8>(obs, obs, V_W1 + (size_t)n * HD * HD, n, tid, lrow, lk8, Nbase,
               wm1, w, lane, Wl0, Wl1, Xl[0], Xl[1], acc);
  __syncthreads();
  gemm2_branch(acc, acc2, V_W2 + (size_t)n * HD * FD, V_b1 + n * HD,
               W_lds, slab, lrow, lq, lk8, Nbase, wm1, wn1, w, lane);

  // ---------------- A branch ----------------
#pragma unroll
  for (int m = 0; m < 8; ++m)
#pragma unroll
    for (int nf = 0; nf < 4; ++nf) acc[m][nf] = (f32x4){0.f, 0.f, 0.f, 0.f};
  run_gemm1<16>(obs, act, A_W1 + (size_t)n * 2 * HD * HD, n, tid, lrow, lk8, Nbase,
                wm1, w, lane, Wl0, Wl1, Xl[0], Xl[1], acc);
  __syncthreads();
  gemm2_branch(acc, acc2, A_W2 + (size_t)n * HD * FD, A_b1 + n * HD,
               W_lds, slab, lrow, lq, lk8, Nbase, wm1, wn1, w, lane);

  // ---------------- Q = acc2 + V_b2 + A_b2 ----------------
  const float* vb2 = V_b2 + n * FD;
  const float* ab2 = A_b2 + n * FD;
#pragma unroll
  for (int mf = 0; mf < 2; ++mf)
#pragma unroll
    for (int nf = 0; nf < 4; ++nf) {
      int f = nf * 16 + lrow;
      float bias = vb2[f] + ab2[f];
#pragma unroll
      for (int rr = 0; rr < 4; ++rr) {
        int row = w * 32 + mf * 16 + lq * 4 + rr;
        Q[(size_t)row * (BN * FD) + n * FD + f] = acc2[mf][nf][rr] + bias;
      }
    }
}

// ---------------- phase 2: gather + subset-min + chi + mean ----------------
__global__ __launch_bounds__(256) void phase2_kernel(const float* __restrict__ Q,
                                                     const float* __restrict__ chi_m,
                                                     const int* __restrict__ le,
                                                     float* __restrict__ out) {
  int b = blockIdx.x;
  int n = threadIdx.x;
  // int64-vs-int32 layout hedge: centers = arange(N) => int32 layout has le[5]==1.
  int step = (le[5] == 1) ? 1 : 2;
  const int* e = le + n * 5 * step;
  int c  = e[0 * step] & (BN - 1);
  int n0 = e[1 * step] & (BN - 1);
  int n1 = e[2 * step] & (BN - 1);
  int n2 = e[3 * step] & (BN - 1);
  int n3 = e[4 * step] & (BN - 1);
  const float* ch = chi_m + n * 45;   // (HEADS=3, S=15)
  float cm[15];
#pragma unroll
  for (int s = 0; s < 15; ++s) cm[s] = (ch[s] + ch[15 + s] + ch[30 + s]) * (1.f / 3.f);
  const float* qb = Q + (size_t)b * (BN * FD);
  const float* q0 = qb + n0 * FD;
  const float* q1 = qb + n1 * FD;
  const float* q2 = qb + n2 * FD;
  const float* q3 = qb + n3 * FD;
  const float* qc = qb + c * FD;
  float acc = 0.f;
#pragma unroll
  for (int f = 0; f < FD; f += 4) {
    float4 v0 = *(const float4*)(q0 + f);
    float4 v1 = *(const float4*)(q1 + f);
    float4 v2 = *(const float4*)(q2 + f);
    float4 v3 = *(const float4*)(q3 + f);
    float4 vc = *(const float4*)(qc + f);
    const float* p0 = (const float*)&v0;
    const float* p1 = (const float*)&v1;
    const float* p2 = (const float*)&v2;
    const float* p3 = (const float*)&v3;
    const float* pc = (const float*)&vc;
#pragma unroll
    for (int u = 0; u < 4; ++u) {
      float a = p0[u], bq = p1[u], cq = p2[u], d = p3[u];
      float m01 = fminf(a, bq), m02 = fminf(a, cq), m03 = fminf(a, d);
      float m12 = fminf(bq, cq), m13 = fminf(bq, d), m23 = fminf(cq, d);
      float m012 = fminf(m01, cq), m013 = fminf(m01, d);
      float m023 = fminf(m02, d),  m123 = fminf(m12, d);
      float m0123 = fminf(m01, m23);
      float chi = cm[0] * a   + cm[1] * bq   + cm[2] * m01  + cm[3] * cq
                + cm[4] * m02 + cm[5] * m12  + cm[6] * m012 + cm[7] * d
                + cm[8] * m03 + cm[9] * m13  + cm[10] * m013 + cm[11] * m23
                + cm[12] * m023 + cm[13] * m123 + cm[14] * m0123;
      acc += chi + pc[u];
    }
  }
  out[b * BN + n] = acc * (1.f / 64.f);
}

extern "C" void kernel_launch(void* const* d_in, const int* in_sizes, int n_in,
                              void* d_out, int out_size, void* d_ws, size_t ws_size,
                              hipStream_t stream) {
  (void)in_sizes; (void)n_in; (void)out_size; (void)ws_size;
  const float* obs  = (const float*)d_in[0];
  const float* act  = (const float*)d_in[1];
  const float* V_W1 = (const float*)d_in[2];
  const float* V_b1 = (const float*)d_in[3];
  const float* V_W2 = (const float*)d_in[4];
  const float* V_b2 = (const float*)d_in[5];
  const float* A_W1 = (const float*)d_in[6];
  const float* A_b1 = (const float*)d_in[7];
  const float* A_W2 = (const float*)d_in[8];
  const float* A_b2 = (const float*)d_in[9];
  const float* chim = (const float*)d_in[10];
  const int*   le   = (const int*)d_in[11];
  float* Q   = (float*)d_ws;            // 16 MB scratch: Q[B][N][F]
  float* out = (float*)d_out;

  phase1_kernel<<<dim3(256), dim3(512), 0, stream>>>(obs, act, V_W1, V_b1, V_W2, V_b2,
                                                     A_W1, A_b1, A_W2, A_b2, Q);
  phase2_kernel<<<dim3(256), dim3(256), 0, stream>>>(Q, chim, le, out);
}

// Round 9
// 116.509 us; speedup vs baseline: 2.1255x; 1.0088x over previous
//
#include <hip/hip_runtime.h>
#include <cstddef>

// Critic_43104291783486 — round 9: saturate the HBM pump.
//  (a) W ring: 3x32KB buffers, prefetch depth 2 tiles (~64KB/CU in flight).
//  (b) XOR-swizzle W LDS tiles (pre-swizzled gload SOURCE, linear LDS dest;
//      key ((row>>3)&3)<<4) -> B-frag reads go 4-way-conflict -> free 2-way.
//  (c) W2 fetched into the two ring buffers freed during the last 2 GEMM1
//      steps -> GEMM2 starts with W2 resident.
// Unchanged: grid 256 (1 node/CU, weights-once), 512 thr / 8 waves,
// fp16 MFMA 16x16x32 layouts verified r3-r8, X reg->fp16 LDS staging.

#define BN 256
#define HD 256
#define FD 64
#define XS 40    // X lds row stride (halves)
#define SLS 268  // slab row stride (halves)

typedef _Float16 f16x8 __attribute__((ext_vector_type(8)));
typedef _Float16 f16x4 __attribute__((ext_vector_type(4)));
typedef float f32x4 __attribute__((ext_vector_type(4)));

#define GLOAD16(g, l)                                              \
  __builtin_amdgcn_global_load_lds(                                \
      (__attribute__((address_space(1))) void*)(g),                \
      (__attribute__((address_space(3))) void*)(l), 16, 0, 0)

#define WAIT_BAR(VMCNT_STR)                                        \
  asm volatile("s_waitcnt " VMCNT_STR " lgkmcnt(0)" ::: "memory"); \
  __builtin_amdgcn_s_barrier();                                    \
  asm volatile("" ::: "memory");

// ---------- X staging: 256 rows x 32 k fp32 -> regs -> fp16 LDS ----------
__device__ __forceinline__ void x_load(const float* xs0, const float* xs1, int n,
                                       int kt, int tid, float4 xr[4]) {
  int kOff = kt * 32;
  const float* xs = (kOff < 256) ? xs0 : xs1;   // A-branch: obs then act
  int l = tid & 63, w = tid >> 6;
  const float* base = xs + (size_t)n * HD + (kOff & 255) + (l & 7) * 4;
#pragma unroll
  for (int i = 0; i < 4; ++i) {
    int row = w * 32 + i * 8 + (l >> 3);
    xr[i] = *(const float4*)(base + (size_t)row * (BN * HD));
  }
}
__device__ __forceinline__ void x_write(_Float16* Xl, int tid, const float4 xr[4]) {
  int l = tid & 63, w = tid >> 6;
#pragma unroll
  for (int i = 0; i < 4; ++i) {
    int row = w * 32 + i * 8 + (l >> 3);
    f16x4 v;
    v[0] = (_Float16)xr[i].x; v[1] = (_Float16)xr[i].y;
    v[2] = (_Float16)xr[i].z; v[3] = (_Float16)xr[i].w;
    *(f16x4*)(Xl + row * XS + (l & 7) * 4) = v;
  }
}

// ---------- W1 tile gload: [32][256] fp32, source pre-swizzled ----------
// LDS[rl][c'] = W[row][c' ^ ((rl>>3)&3)<<4]; reader XORs the same key.
__device__ __forceinline__ void w1_gload(const float* __restrict__ Wg, float* Wl,
                                         int ktile, int w, int lane) {
#pragma unroll
  for (int s = 0; s < 4; ++s) {
    int rl = w * 4 + s;                       // local row 0..31
    int swz = ((rl >> 3) & 3) << 4;
    const float* src = Wg + (size_t)(ktile * 32 + rl) * HD + ((lane * 4) ^ swz);
    GLOAD16(src, Wl + rl * HD);
  }
}

// ---------- W2 half gload: rows half*128..+127 of W2(256x64) -> chunk[128][64] ----------
__device__ __forceinline__ void w2_gload_half(const float* __restrict__ W2g, float* chunk,
                                              int half, int w, int lane) {
#pragma unroll
  for (int s = 0; s < 4; ++s) {
    int rl = (w * 4 + s) * 4;                 // local row base (mult of 4)
    int swz = ((rl >> 3) & 3) << 4;           // uniform for rl..rl+3
    const float* src = W2g + (size_t)(half * 128 + rl + (lane >> 4)) * FD
                       + (((lane & 15) * 4) ^ swz);
    GLOAD16(src, chunk + rl * FD);
  }
}

// ---------- GEMM1 compute: one 32-k step, 32 MFMA/wave ----------
// A-frag: row = wm1*128+m*16+(l&15), k = lq*8+j. B-frag swizzle-read.
__device__ __forceinline__ void g1_compute(const float* Wc, const _Float16* Xc,
                                           int lrow, int lq, int Nbase, int wm1,
                                           f32x4 acc[8][4]) {
  int lk8 = lq * 8;
  const float* wbase = Wc + lk8 * 256;
  f16x8 b[4];
#pragma unroll
  for (int nf = 0; nf < 4; ++nf) {
    int col = (Nbase + nf * 16 + lrow) ^ (lq << 4);
    f16x8 t;
#pragma unroll
    for (int j = 0; j < 8; ++j) t[j] = (_Float16)wbase[j * 256 + col];
    b[nf] = t;
  }
#pragma unroll
  for (int m = 0; m < 8; ++m) {
    f16x8 a = *(const f16x8*)(Xc + (wm1 * 128 + m * 16 + lrow) * XS + lk8);
#pragma unroll
    for (int nf = 0; nf < 4; ++nf)
      acc[m][nf] = __builtin_amdgcn_mfma_f32_16x16x32_f16(a, b[nf], acc[m][nf], 0, 0, 0);
  }
}

// C(256x256) = X(256xK) @ W1(Kx256), K = NK*32 (NK even). Ring of 3 W buffers;
// W2 halves fetched into the 2 buffers freed during the last 2 steps.
template <int NK>
__device__ __forceinline__ void run_gemm1(const float* xs0, const float* xs1,
                                          const float* __restrict__ Wg,
                                          const float* __restrict__ W2g,
                                          int n, int tid, int lrow, int lq,
                                          int Nbase, int wm1, int w, int lane,
                                          float* Wring, _Float16* Xl0, _Float16* Xl1,
                                          f32x4 acc[8][4]) {
  float* w0 = Wring;            // W(kt)
  float* w1 = Wring + 8192;     // W(kt+1)
  float* w2 = Wring + 16384;    // free -> W(kt+2)
  float4 xrA[4], xrB[4];
  x_load(xs0, xs1, n, 0, tid, xrA);
  w1_gload(Wg, w0, 0, w, lane);
  x_load(xs0, xs1, n, 1, tid, xrB);
  w1_gload(Wg, w1, 1, w, lane);
  x_write(Xl0, tid, xrA);          // auto-wait drains X(0); keeps W0,X1,W1
  WAIT_BAR("vmcnt(8)")             // drain W(0); X(1),W(1) stay in flight
#pragma unroll 1
  for (int kt = 0; kt < NK; kt += 2) {
    // ---- even sub-step: compute (w0, Xl0) ----
    if (kt + 2 < NK) {
      x_load(xs0, xs1, n, kt + 2, tid, xrA);
      w1_gload(Wg, w2, kt + 2, w, lane);
    } else {
      w2_gload_half(W2g, w2, 0, w, lane);      // kt == NK-2
    }
    g1_compute(w0, Xl0, lrow, lq, Nbase, wm1, acc);
    if (kt + 1 < NK) x_write(Xl1, tid, xrB);   // drains X(kt+1) only
    if (kt < NK - 2) { WAIT_BAR("vmcnt(8)") }  // drain W(kt+1); 2 tiles in flight
    else             { WAIT_BAR("vmcnt(4)") }  // drain W(NK-1); keep W2a
    { float* t = w0; w0 = w1; w1 = w2; w2 = t; }
    // ---- odd sub-step: compute (w0, Xl1) ----
    if (kt + 3 < NK) {
      x_load(xs0, xs1, n, kt + 3, tid, xrB);
      w1_gload(Wg, w2, kt + 3, w, lane);
    } else {
      w2_gload_half(W2g, w2, 1, w, lane);      // kt+1 == NK-1
    }
    g1_compute(w0, Xl1, lrow, lq, Nbase, wm1, acc);
    if (kt + 2 < NK) {
      x_write(Xl0, tid, xrA);
      WAIT_BAR("vmcnt(8)")
    }                                          // last step: no write, no wait
    { float* t = w0; w0 = w1; w1 = w2; w2 = t; }
  }
  // caller __syncthreads() drains W2a+W2b and closes LDS hazards
}

// ---------- GEMM2: C2(256x64) += relu(C1+b1) @ W2 (resident in cA/cB) ----------
__device__ __forceinline__ void gemm2_branch(f32x4 acc[8][4], f32x4 acc2[2][4],
                                             const float* cA, const float* cB,
                                             const float* __restrict__ b1g,
                                             _Float16* slab, int lrow, int lq,
                                             int Nbase, int wm1, int wn1, int w) {
  int lk8 = lq * 8;
  float bv[4];
#pragma unroll
  for (int nf = 0; nf < 4; ++nf) bv[nf] = b1g[Nbase + nf * 16 + lrow];
#pragma unroll 1
  for (int s = 0; s < 4; ++s) {
    if (wn1 == s) {                       // 2 waves own this 64-col slab of C1
#pragma unroll
      for (int m = 0; m < 8; ++m)
#pragma unroll
        for (int nf = 0; nf < 4; ++nf) {
          f16x4 hv;
#pragma unroll
          for (int r = 0; r < 4; ++r)
            hv[r] = (_Float16)fmaxf(acc[m][nf][r] + bv[nf], 0.f);
          *(f16x4*)(slab + (nf * 16 + lrow) * SLS + wm1 * 128 + m * 16 + lq * 4) = hv;
        }
    }
    __syncthreads();
#pragma unroll
    for (int kf = 0; kf < 2; ++kf) {
      const int r0 = s * 64 + kf * 32;
      const float* wb2 = ((r0 < 128) ? cA : cB) + ((r0 & 127) + lk8) * FD;
      f16x8 a2[2], bb[4];
#pragma unroll
      for (int mf = 0; mf < 2; ++mf) {
        f16x8 t;
#pragma unroll
        for (int j = 0; j < 8; ++j)
          t[j] = slab[(kf * 32 + lk8 + j) * SLS + w * 32 + mf * 16 + lrow];
        a2[mf] = t;
      }
#pragma unroll
      for (int nf = 0; nf < 4; ++nf) {
        int col = (nf * 16 + lrow) ^ (lq << 4);
        f16x8 t;
#pragma unroll
        for (int j = 0; j < 8; ++j) t[j] = (_Float16)wb2[j * FD + col];
        bb[nf] = t;
      }
#pragma unroll
      for (int mf = 0; mf < 2; ++mf)
#pragma unroll
        for (int nf = 0; nf < 4; ++nf)
          acc2[mf][nf] =
              __builtin_amdgcn_mfma_f32_16x16x32_f16(a2[mf], bb[nf], acc2[mf][nf], 0, 0, 0);
    }
    __syncthreads();
  }
}

__global__ __launch_bounds__(512, 2) void phase1_kernel(
    const float* __restrict__ obs, const float* __restrict__ act,
    const float* __restrict__ V_W1, const float* __restrict__ V_b1,
    const float* __restrict__ V_W2, const float* __restrict__ V_b2,
    const float* __restrict__ A_W1, const float* __restrict__ A_b1,
    const float* __restrict__ A_W2, const float* __restrict__ A_b2,
    float* __restrict__ Q) {
  // [0,96KB): W ring (3x32KB).  [96KB,136KB): X double-buffer (GEMM1) / slab (GEMM2).
  __shared__ __align__(16) float smem[34816];           // 136 KB
  float* Wring = smem;
  _Float16* Xl0 = (_Float16*)(smem + 24576);
  _Float16* Xl1 = Xl0 + 10240;
  _Float16* slab = (_Float16*)(smem + 24576);

  int tid = threadIdx.x;
  int l = tid & 63, w = tid >> 6, lane = l;
  int lrow = l & 15, lq = l >> 4;
  int wm1 = w >> 2, wn1 = w & 3;      // GEMM1 wave grid 2M x 4N
  int Nbase = wn1 * 64;
  int n = blockIdx.x;                 // 1 node per block per CU

  f32x4 acc[8][4];
  f32x4 acc2[2][4];
#pragma unroll
  for (int i = 0; i < 2; ++i)
#pragma unroll
    for (int j = 0; j < 4; ++j) acc2[i][j] = (f32x4){0.f, 0.f, 0.f, 0.f};

  // ---------------- V branch (NK=8; W2 chunks land in buf2, buf0) ----------------
#pragma unroll
  for (int m = 0; m < 8; ++m)
#pragma unroll
    for (int nf = 0; nf < 4; ++nf) acc[m][nf] = (f32x4){0.f, 0.f, 0.f, 0.f};
  run_gemm1<8>(obs, obs, V_W1 + (size_t)n * HD * HD, V_W2 + (size_t)n * HD * FD,
               n, tid, lrow, lq, Nbase, wm1, w, lane, Wring, Xl0, Xl1, acc);
  __syncthreads();                    // drains W2 gloads + LDS hazards
  gemm2_branch(acc, acc2, Wring + 16384 /*buf (8%3)=2*/, Wring /*buf (9%3)=0*/,
               V_b1 + n * HD, slab, lrow, lq, Nbase, wm1, wn1, w);

  // ---------------- A branch (NK=16; W2 chunks land in buf1, buf2) ----------------
#pragma unroll
  for (int m = 0; m < 8; ++m)
#pragma unroll
    for (int nf = 0; nf < 4; ++nf) acc[m][nf] = (f32x4){0.f, 0.f, 0.f, 0.f};
  run_gemm1<16>(obs, act, A_W1 + (size_t)n * 2 * HD * HD, A_W2 + (size_t)n * HD * FD,
                n, tid, lrow, lq, Nbase, wm1, w, lane, Wring, Xl0, Xl1, acc);
  __syncthreads();
  gemm2_branch(acc, acc2, Wring + 8192 /*buf (16%3)=1*/, Wring + 16384 /*buf (17%3)=2*/,
               A_b1 + n * HD, slab, lrow, lq, Nbase, wm1, wn1, w);

  // ---------------- Q = acc2 + V_b2 + A_b2 ----------------
  const float* vb2 = V_b2 + n * FD;
  const float* ab2 = A_b2 + n * FD;
#pragma unroll
  for (int mf = 0; mf < 2; ++mf)
#pragma unroll
    for (int nf = 0; nf < 4; ++nf) {
      int f = nf * 16 + lrow;
      float bias = vb2[f] + ab2[f];
#pragma unroll
      for (int rr = 0; rr < 4; ++rr) {
        int row = w * 32 + mf * 16 + lq * 4 + rr;
        Q[(size_t)row * (BN * FD) + n * FD + f] = acc2[mf][nf][rr] + bias;
      }
    }
}

// ---------------- phase 2: gather + subset-min + chi + mean ----------------
__global__ __launch_bounds__(256) void phase2_kernel(const float* __restrict__ Q,
                                                     const float* __restrict__ chi_m,
                                                     const int* __restrict__ le,
                                                     float* __restrict__ out) {
  int b = blockIdx.x;
  int n = threadIdx.x;
  // int64-vs-int32 layout hedge: centers = arange(N) => int32 layout has le[5]==1.
  int step = (le[5] == 1) ? 1 : 2;
  const int* e = le + n * 5 * step;
  int c  = e[0 * step] & (BN - 1);
  int n0 = e[1 * step] & (BN - 1);
  int n1 = e[2 * step] & (BN - 1);
  int n2 = e[3 * step] & (BN - 1);
  int n3 = e[4 * step] & (BN - 1);
  const float* ch = chi_m + n * 45;   // (HEADS=3, S=15)
  float cm[15];
#pragma unroll
  for (int s = 0; s < 15; ++s) cm[s] = (ch[s] + ch[15 + s] + ch[30 + s]) * (1.f / 3.f);
  const float* qb = Q + (size_t)b * (BN * FD);
  const float* q0 = qb + n0 * FD;
  const float* q1 = qb + n1 * FD;
  const float* q2 = qb + n2 * FD;
  const float* q3 = qb + n3 * FD;
  const float* qc = qb + c * FD;
  float acc = 0.f;
#pragma unroll
  for (int f = 0; f < FD; f += 4) {
    float4 v0 = *(const float4*)(q0 + f);
    float4 v1 = *(const float4*)(q1 + f);
    float4 v2 = *(const float4*)(q2 + f);
    float4 v3 = *(const float4*)(q3 + f);
    float4 vc = *(const float4*)(qc + f);
    const float* p0 = (const float*)&v0;
    const float* p1 = (const float*)&v1;
    const float* p2 = (const float*)&v2;
    const float* p3 = (const float*)&v3;
    const float* pc = (const float*)&vc;
#pragma unroll
    for (int u = 0; u < 4; ++u) {
      float a = p0[u], bq = p1[u], cq = p2[u], d = p3[u];
      float m01 = fminf(a, bq), m02 = fminf(a, cq), m03 = fminf(a, d);
      float m12 = fminf(bq, cq), m13 = fminf(bq, d), m23 = fminf(cq, d);
      float m012 = fminf(m01, cq), m013 = fminf(m01, d);
      float m023 = fminf(m02, d),  m123 = fminf(m12, d);
      float m0123 = fminf(m01, m23);
      float chi = cm[0] * a   + cm[1] * bq   + cm[2] * m01  + cm[3] * cq
                + cm[4] * m02 + cm[5] * m12  + cm[6] * m012 + cm[7] * d
                + cm[8] * m03 + cm[9] * m13  + cm[10] * m013 + cm[11] * m23
                + cm[12] * m023 + cm[13] * m123 + cm[14] * m0123;
      acc += chi + pc[u];
    }
  }
  out[b * BN + n] = acc * (1.f / 64.f);
}

extern "C" void kernel_launch(void* const* d_in, const int* in_sizes, int n_in,
                              void* d_out, int out_size, void* d_ws, size_t ws_size,
                              hipStream_t stream) {
  (void)in_sizes; (void)n_in; (void)out_size; (void)ws_size;
  const float* obs  = (const float*)d_in[0];
  const float* act  = (const float*)d_in[1];
  const float* V_W1 = (const float*)d_in[2];
  const float* V_b1 = (const float*)d_in[3];
  const float* V_W2 = (const float*)d_in[4];
  const float* V_b2 = (const float*)d_in[5];
  const float* A_W1 = (const float*)d_in[6];
  const float* A_b1 = (const float*)d_in[7];
  const float* A_W2 = (const float*)d_in[8];
  const float* A_b2 = (const float*)d_in[9];
  const float* chim = (const float*)d_in[10];
  const int*   le   = (const int*)d_in[11];
  float* Q   = (float*)d_ws;            // 16 MB scratch: Q[B][N][F]
  float* out = (float*)d_out;

  phase1_kernel<<<dim3(256), dim3(512), 0, stream>>>(obs, act, V_W1, V_b1, V_W2, V_b2,
                                                     A_W1, A_b1, A_W2, A_b2, Q);
  phase2_kernel<<<dim3(256), dim3(256), 0, stream>>>(Q, chim, le, out);
}